// Round 15
// baseline (432.958 us; speedup 1.0000x reference)
//
#include <hip/hip_runtime.h>
#include <hip/hip_bf16.h>

#define NN 100000
#define EE 1250000
#define DD 64
#define GG 256
#define COARSE 1024
#define NC ((NN + COARSE - 1) / COARSE)     // 98 coarse buckets
#define CHUNK 2048
#define NCHUNK ((EE + CHUNK - 1) / CHUNK)   // 611

static __device__ __forceinline__ float relu_f(float x) { return fmaxf(x, 0.0f); }

static __device__ __forceinline__ float b2f(ushort u) {
    return __uint_as_float(((unsigned int)u) << 16);
}
static __device__ __forceinline__ ushort f2b(float f) {
    __hip_bfloat16 h = __float2bfloat16(f);  // RNE
    return *(ushort*)&h;
}

// ---------------- coarse histogram (LDS pre-aggregated) ----------------
__global__ __launch_bounds__(256) void hist2_kernel(const int* __restrict__ dst,
                                                    int* __restrict__ ghist, int E) {
    __shared__ int h[NC];
    int t = threadIdx.x;
    if (t < NC) h[t] = 0;
    __syncthreads();
    for (int e = blockIdx.x * blockDim.x + t; e < E; e += gridDim.x * blockDim.x)
        atomicAdd(&h[dst[e] >> 10], 1);
    __syncthreads();
    if (t < NC && h[t]) atomicAdd(&ghist[t], h[t]);
}

// tiny scan over NC=98
__global__ void scan2_kernel(const int* __restrict__ ghist, int* __restrict__ coffs,
                             int* __restrict__ gcursor) {
    if (threadIdx.x == 0) {
        int run = 0;
        for (int b = 0; b < NC; b++) {
            coffs[b] = run;
            gcursor[b] = run;
            run += ghist[b];
        }
        coffs[NC] = run;
    }
}

// ---------------- LDS-binned scatter: coalesced bucket-run writes ----------------
// pack = src (17b) | dstLocal (10b) << 17
__global__ __launch_bounds__(256) void bin_kernel(
    const int* __restrict__ ei, int* __restrict__ gcursor, int* __restrict__ epack, int E) {
    __shared__ int hist[NC];
    __shared__ int base[NC];
    __shared__ int lpre[NC];
    __shared__ int scnt;
    __shared__ int lbuf[CHUNK];
    __shared__ int lobuf[CHUNK];
    int t = threadIdx.x;
    for (int c = blockIdx.x; c < NCHUNK; c += gridDim.x) {
        int e0 = c * CHUNK;
        if (t < NC) hist[t] = 0;
        __syncthreads();
        int myb[8], myloc[8], mypack[8];
#pragma unroll
        for (int q = 0; q < 8; q++) {
            int e = e0 + q * 256 + t;
            if (e < E) {
                int d = ei[E + e];
                int s = ei[e];
                int b = d >> 10;
                myb[q] = b;
                mypack[q] = s | ((d & (COARSE - 1)) << 17);
                myloc[q] = atomicAdd(&hist[b], 1);
            } else myb[q] = -1;
        }
        __syncthreads();
        if (t < NC) base[t] = hist[t] ? atomicAdd(&gcursor[t], hist[t]) : 0;
        if (t == 0) {
            int run = 0;
            for (int b = 0; b < NC; b++) { lpre[b] = run; run += hist[b]; }
            scnt = run;
        }
        __syncthreads();
#pragma unroll
        for (int q = 0; q < 8; q++) {
            if (myb[q] >= 0) {
                int p = lpre[myb[q]] + myloc[q];
                lbuf[p] = mypack[q];
                lobuf[p] = base[myb[q]] + myloc[q];
            }
        }
        __syncthreads();
        int cnt = scnt;
#pragma unroll
        for (int q = 0; q < 8; q++) {
            int p = q * 256 + t;
            if (p < cnt) epack[lobuf[p]] = lbuf[p];   // consecutive p -> consecutive dest
        }
        __syncthreads();
    }
}

// ---------------- per-coarse-bucket exact CSR build (block-private window) ------
__global__ __launch_bounds__(256) void csr2_kernel(
    const int* __restrict__ epack, const int* __restrict__ coffs,
    int* __restrict__ srcs, int* __restrict__ off) {
    __shared__ int hist[COARSE];   // counts -> then cursors
    __shared__ int tmp[256];
    int b = blockIdx.x;
    int t = threadIdx.x;
    int c0 = coffs[b], c1 = coffs[b + 1];
    int nbase = b * COARSE;
#pragma unroll
    for (int j = 0; j < 4; j++) hist[t * 4 + j] = 0;
    __syncthreads();
    for (int e = c0 + t; e < c1; e += 256)
        atomicAdd(&hist[epack[e] >> 17], 1);
    __syncthreads();
    int h0 = hist[t * 4], h1 = hist[t * 4 + 1], h2 = hist[t * 4 + 2], h3 = hist[t * 4 + 3];
    int s4 = h0 + h1 + h2 + h3;
    tmp[t] = s4;
    __syncthreads();
    for (int d = 1; d < 256; d <<= 1) {
        int v = (t >= d) ? tmp[t - d] : 0;
        __syncthreads();
        tmp[t] += v;
        __syncthreads();
    }
    int run = tmp[t] - s4;
    int pre0 = run; run += h0;
    int pre1 = run; run += h1;
    int pre2 = run; run += h2;
    int pre3 = run;
    int pres[4] = {pre0, pre1, pre2, pre3};
#pragma unroll
    for (int j = 0; j < 4; j++) {
        int node = nbase + t * 4 + j;
        if (node < NN) off[node] = c0 + pres[j];
        hist[t * 4 + j] = pres[j];   // reuse as cursor
    }
    if (b == NC - 1 && t == 0) off[NN] = c1;
    __syncthreads();
    for (int e = c0 + t; e < c1; e += 256) {
        int p = epack[e];
        int pos = c0 + atomicAdd(&hist[p >> 17], 1);
        srcs[pos] = p & 0x1FFFF;
    }
}

// graph boundaries from sorted batch
__global__ void bounds_kernel(const int* __restrict__ batch, int* __restrict__ gstart, int n) {
    int i = blockIdx.x * blockDim.x + threadIdx.x;
    if (i >= n) return;
    int b = batch[i];
    int prev = (i == 0) ? -1 : batch[i - 1];
    for (int g = prev + 1; g <= b; g++) gstart[g] = i;
    if (i == n - 1) {
        for (int g = b + 1; g <= GG; g++) gstart[g] = n;
    }
}

// fp32 -> bf16 cast of x (once)
__global__ __launch_bounds__(256) void cast_kernel(const float* __restrict__ x,
                                                   ushort* __restrict__ xb) {
    size_t i = ((size_t)blockIdx.x * blockDim.x + threadIdx.x) * 4;
    if (i >= (size_t)NN * DD) return;
    float4 v = *(const float4*)(x + i);
    ushort4 r;
    r.x = f2b(v.x); r.y = f2b(v.y); r.z = f2b(v.z); r.w = f2b(v.w);
    *(ushort4*)(xb + i) = r;
}

// ---------------- fused agg + MLP per layer -----------------------------------
// Block = 64 nodes, 4 waves. Phase 1: wave w aggregates nodes w*16..w*16+15
// (round-11's proven 8/4/1 gather loops, lane = feature) writing u DIRECTLY
// into At[feature][node_local] (the transpose the old staging did). Phase 2:
// round-10's proven tiled GEMM/epilogue. Eliminates the 25MB bufU write+read
// per layer and 3 launches; u stays fp32 -> bit-identical math to round 11.
template <bool HAS_BN, bool OUT_BF16>
__global__ __launch_bounds__(256) void fused_kernel(
    const ushort* __restrict__ xin, void* __restrict__ hout,
    const int* __restrict__ off, const int* __restrict__ srcs,
    const float* __restrict__ wa, const float* __restrict__ ba,
    const float* __restrict__ wb, const float* __restrict__ bb,
    const float* __restrict__ bng, const float* __restrict__ bnb,
    const float* __restrict__ bnm, const float* __restrict__ bnv, int n) {
    __shared__ float At[DD][68];   // At[feature][node_local]; 68-pad, rows 16B-aligned
    __shared__ float Wt[DD * DD];  // W[k][j] row-major
    int t = threadIdx.x;
    int r0 = blockIdx.x * DD;
    int wave = t >> 6, lane = t & 63;

    // stage Wa (overlaps with gather latency below)
#pragma unroll
    for (int rep = 0; rep < 4; rep++) {
        int idx = rep * 1024 + t * 4;
        *(float4*)&Wt[idx] = *(const float4*)&wa[idx];
    }

    // ---- phase 1: aggregation (r11 structure), u -> At[lane][i] ----
    for (int q = 0; q < 16; q++) {
        int i = wave * 16 + q;
        int node = r0 + i;
        if (node < n) {
            int o = off[node], oe = off[node + 1];
            float a0 = b2f(xin[(size_t)node * DD + lane]);   // self
            float a1 = 0.0f, a2 = 0.0f, a3 = 0.0f, a4 = 0.0f, a5 = 0.0f, a6 = 0.0f, a7 = 0.0f;
            int j = o;
            for (; j + 8 <= oe; j += 8) {
                int s0 = srcs[j + 0], s1 = srcs[j + 1], s2 = srcs[j + 2], s3 = srcs[j + 3];
                int s4 = srcs[j + 4], s5 = srcs[j + 5], s6 = srcs[j + 6], s7 = srcs[j + 7];
                ushort v0 = xin[(size_t)s0 * DD + lane];
                ushort v1 = xin[(size_t)s1 * DD + lane];
                ushort v2 = xin[(size_t)s2 * DD + lane];
                ushort v3 = xin[(size_t)s3 * DD + lane];
                ushort v4 = xin[(size_t)s4 * DD + lane];
                ushort v5 = xin[(size_t)s5 * DD + lane];
                ushort v6 = xin[(size_t)s6 * DD + lane];
                ushort v7 = xin[(size_t)s7 * DD + lane];
                a0 += b2f(v0); a1 += b2f(v1); a2 += b2f(v2); a3 += b2f(v3);
                a4 += b2f(v4); a5 += b2f(v5); a6 += b2f(v6); a7 += b2f(v7);
            }
            for (; j + 4 <= oe; j += 4) {
                int s0 = srcs[j + 0], s1 = srcs[j + 1], s2 = srcs[j + 2], s3 = srcs[j + 3];
                ushort v0 = xin[(size_t)s0 * DD + lane];
                ushort v1 = xin[(size_t)s1 * DD + lane];
                ushort v2 = xin[(size_t)s2 * DD + lane];
                ushort v3 = xin[(size_t)s3 * DD + lane];
                a0 += b2f(v0); a1 += b2f(v1); a2 += b2f(v2); a3 += b2f(v3);
            }
            for (; j < oe; j++) a0 += b2f(xin[(size_t)srcs[j] * DD + lane]);
            At[lane][i] = ((a0 + a1) + (a2 + a3)) + ((a4 + a5) + (a6 + a7));
        } else {
            At[lane][i] = 0.0f;
        }
    }
    __syncthreads();

    // ---- phase 2: tiled GEMM MLP (r10 structure) ----
    int tx = t & 15, ty = t >> 4;
    int i0 = tx * 4, j0 = ty * 4;

    float acc[4][4];
#pragma unroll
    for (int a = 0; a < 4; a++)
#pragma unroll
        for (int b = 0; b < 4; b++) acc[a][b] = 0.0f;
#pragma unroll 4
    for (int k = 0; k < DD; k++) {
        float4 av = *(const float4*)&At[k][i0];
        float4 wv = *(const float4*)&Wt[k * DD + j0];
        float aa[4] = {av.x, av.y, av.z, av.w};
        float ww[4] = {wv.x, wv.y, wv.z, wv.w};
#pragma unroll
        for (int di = 0; di < 4; di++)
#pragma unroll
            for (int dj = 0; dj < 4; dj++)
                acc[di][dj] = fmaf(aa[di], ww[dj], acc[di][dj]);
    }
    float4 ba4 = *(const float4*)&ba[j0];
    float bav[4] = {ba4.x, ba4.y, ba4.z, ba4.w};
    __syncthreads();   // all At/Wt reads done

    // write z1^T into At; stage Wb
#pragma unroll
    for (int dj = 0; dj < 4; dj++) {
        float4 w;
        w.x = relu_f(acc[0][dj] + bav[dj]);
        w.y = relu_f(acc[1][dj] + bav[dj]);
        w.z = relu_f(acc[2][dj] + bav[dj]);
        w.w = relu_f(acc[3][dj] + bav[dj]);
        *(float4*)&At[j0 + dj][i0] = w;
    }
#pragma unroll
    for (int rep = 0; rep < 4; rep++) {
        int idx = rep * 1024 + t * 4;
        *(float4*)&Wt[idx] = *(const float4*)&wb[idx];
    }
    __syncthreads();

    float acc2[4][4];
#pragma unroll
    for (int a = 0; a < 4; a++)
#pragma unroll
        for (int b = 0; b < 4; b++) acc2[a][b] = 0.0f;
#pragma unroll 4
    for (int k = 0; k < DD; k++) {
        float4 av = *(const float4*)&At[k][i0];
        float4 wv = *(const float4*)&Wt[k * DD + j0];
        float aa[4] = {av.x, av.y, av.z, av.w};
        float ww[4] = {wv.x, wv.y, wv.z, wv.w};
#pragma unroll
        for (int di = 0; di < 4; di++)
#pragma unroll
            for (int dj = 0; dj < 4; dj++)
                acc2[di][dj] = fmaf(aa[di], ww[dj], acc2[di][dj]);
    }

    float4 bb4 = *(const float4*)&bb[j0];
    float bbv[4] = {bb4.x, bb4.y, bb4.z, bb4.w};
    float scv[4] = {0, 0, 0, 0}, shv[4] = {0, 0, 0, 0};
    if (HAS_BN) {
        float4 g4 = *(const float4*)&bng[j0];
        float4 b4 = *(const float4*)&bnb[j0];
        float4 m4 = *(const float4*)&bnm[j0];
        float4 v4 = *(const float4*)&bnv[j0];
        float gg[4] = {g4.x, g4.y, g4.z, g4.w};
        float bbn[4] = {b4.x, b4.y, b4.z, b4.w};
        float mm[4] = {m4.x, m4.y, m4.z, m4.w};
        float vv[4] = {v4.x, v4.y, v4.z, v4.w};
#pragma unroll
        for (int c = 0; c < 4; c++) {
            scv[c] = gg[c] * rsqrtf(vv[c] + 1e-5f);
            shv[c] = bbn[c] - mm[c] * scv[c];
        }
    }
#pragma unroll
    for (int di = 0; di < 4; di++) {
        int row = r0 + i0 + di;
        if (row >= n) break;
        float v[4];
#pragma unroll
        for (int dj = 0; dj < 4; dj++) {
            float tv = relu_f(acc2[di][dj] + bbv[dj]);
            if (HAS_BN) tv = fmaf(tv, scv[dj], shv[dj]);
            v[dj] = tv;
        }
        if (OUT_BF16) {
            ushort4 r;
            r.x = f2b(v[0]); r.y = f2b(v[1]); r.z = f2b(v[2]); r.w = f2b(v[3]);
            *(ushort4*)((ushort*)hout + (size_t)row * DD + j0) = r;
        } else {
            float4 r; r.x = v[0]; r.y = v[1]; r.z = v[2]; r.w = v[3];
            *(float4*)((float*)hout + (size_t)row * DD + j0) = r;
        }
    }
}

// ---------------- fused pooling + head: one block per graph -----------------
__global__ __launch_bounds__(256) void poolhead_kernel(
    const float* __restrict__ h, const int* __restrict__ gstart,
    const float* __restrict__ wp1, const float* __restrict__ bp1,
    const float* __restrict__ wp2, const float* __restrict__ bp2,
    float* __restrict__ out) {
    __shared__ float ssum[4][DD];
    __shared__ float smax[4][DD];
    __shared__ float gx[2 * DD];
    int g = blockIdx.x;
    int lane = threadIdx.x & 63;
    int wave = threadIdx.x >> 6;
    int s = gstart[g], e = gstart[g + 1];
    float sum = 0.0f, mx = 0.0f;  // layer-2 out is post-ReLU >= 0; 0 == empty-graph guard
    for (int i = s + wave; i < e; i += 4) {
        float v = h[(size_t)i * DD + lane];
        sum += v;
        mx = fmaxf(mx, v);
    }
    ssum[wave][lane] = sum;
    smax[wave][lane] = mx;
    __syncthreads();
    if (wave == 0) {
        sum = ssum[0][lane] + ssum[1][lane] + ssum[2][lane] + ssum[3][lane];
        mx = fmaxf(fmaxf(smax[0][lane], smax[1][lane]),
                   fmaxf(smax[2][lane], smax[3][lane]));
        float cnt = fmaxf((float)(e - s), 1.0f);
        gx[lane] = sum / cnt;
        gx[DD + lane] = mx;
    }
    __syncthreads();
    if (wave == 0) {
        float tt = bp1[lane];
        for (int k = 0; k < 2 * DD; k++) tt = fmaf(gx[k], wp1[k * DD + lane], tt);
        float p0 = tt * wp2[lane * 2 + 0];
        float p1 = tt * wp2[lane * 2 + 1];
        for (int o = 32; o > 0; o >>= 1) {
            p0 += __shfl_down(p0, o);
            p1 += __shfl_down(p1, o);
        }
        if (lane == 0) {
            p0 += bp2[0];
            p1 += bp2[1];
            float m = fmaxf(p0, p1);
            float lse = m + logf(expf(p0 - m) + expf(p1 - m));
            out[g * 2 + 0] = p0 - lse;
            out[g * 2 + 1] = p1 - lse;
        }
    }
}

// ---------------- launch ----------------
extern "C" void kernel_launch(void* const* d_in, const int* in_sizes, int n_in,
                              void* d_out, int out_size, void* d_ws, size_t ws_size,
                              hipStream_t stream) {
    const float* x     = (const float*)d_in[0];
    const int*   ei    = (const int*)d_in[1];
    const int*   batch = (const int*)d_in[2];
    const float* w0a = (const float*)d_in[3];  const float* b0a = (const float*)d_in[4];
    const float* w0b = (const float*)d_in[5];  const float* b0b = (const float*)d_in[6];
    const float* w1a = (const float*)d_in[7];  const float* b1a = (const float*)d_in[8];
    const float* w1b = (const float*)d_in[9];  const float* b1b = (const float*)d_in[10];
    const float* w2a = (const float*)d_in[11]; const float* b2a = (const float*)d_in[12];
    const float* w2b = (const float*)d_in[13]; const float* b2b = (const float*)d_in[14];
    const float* bn0g = (const float*)d_in[15]; const float* bn0b = (const float*)d_in[16];
    const float* bn0m = (const float*)d_in[17]; const float* bn0v = (const float*)d_in[18];
    const float* bn1g = (const float*)d_in[19]; const float* bn1b = (const float*)d_in[20];
    const float* bn1m = (const float*)d_in[21]; const float* bn1v = (const float*)d_in[22];
    const float* wp1 = (const float*)d_in[23]; const float* bp1 = (const float*)d_in[24];
    const float* wp2 = (const float*)d_in[25]; const float* bp2 = (const float*)d_in[26];
    float* out = (float*)d_out;

    char* p = (char*)d_ws;
    auto take = [&](size_t bytes) {
        char* r = p;
        p += (bytes + 255) & ~(size_t)255;
        return r;
    };
    int* ghist   = (int*)take(NC * sizeof(int));
    int* coffs   = (int*)take((NC + 1) * sizeof(int));
    int* gcursor = (int*)take(NC * sizeof(int));
    int* epack   = (int*)take(EE * sizeof(int));
    int* srcs    = (int*)take(EE * sizeof(int));
    int* off     = (int*)take((NN + 1) * sizeof(int));
    int* gstart  = (int*)take((GG + 1) * sizeof(int));
    ushort* xb   = (ushort*)take((size_t)NN * DD * sizeof(ushort));
    ushort* hA   = (ushort*)take((size_t)NN * DD * sizeof(ushort));
    ushort* hB   = (ushort*)take((size_t)NN * DD * sizeof(ushort));
    float* hC    = (float*)take((size_t)NN * DD * sizeof(float));

    // CSR build: coarse hist -> scan -> LDS-binned scatter -> per-bucket CSR
    hipMemsetAsync(ghist, 0, NC * sizeof(int), stream);
    hist2_kernel<<<512, 256, 0, stream>>>(ei + EE, ghist, EE);
    scan2_kernel<<<1, 64, 0, stream>>>(ghist, coffs, gcursor);
    bin_kernel<<<512, 256, 0, stream>>>(ei, gcursor, epack, EE);
    csr2_kernel<<<NC, 256, 0, stream>>>(epack, coffs, srcs, off);
    bounds_kernel<<<(NN + 255) / 256, 256, 0, stream>>>(batch, gstart, NN);
    cast_kernel<<<(NN * DD / 4 + 255) / 256, 256, 0, stream>>>(x, xb);

    int fuse_grid = (NN + DD - 1) / DD;   // 1563 blocks of 64 nodes

    // layer 0: xb -> hA (bf16)
    fused_kernel<true, true><<<fuse_grid, 256, 0, stream>>>(
        xb, hA, off, srcs, w0a, b0a, w0b, b0b, bn0g, bn0b, bn0m, bn0v, NN);
    // layer 1: hA -> hB (bf16)
    fused_kernel<true, true><<<fuse_grid, 256, 0, stream>>>(
        hA, hB, off, srcs, w1a, b1a, w1b, b1b, bn1g, bn1b, bn1m, bn1v, NN);
    // layer 2: hB -> hC (fp32)
    fused_kernel<false, false><<<fuse_grid, 256, 0, stream>>>(
        hB, hC, off, srcs, w2a, b2a, w2b, b2b, nullptr, nullptr, nullptr, nullptr, NN);

    // fused pooling + head
    poolhead_kernel<<<GG, 256, 0, stream>>>(hC, gstart, wp1, bp1, wp2, bp2, out);
}

// Round 16
// 341.345 us; speedup vs baseline: 1.2684x; 1.2684x over previous
//
#include <hip/hip_runtime.h>
#include <hip/hip_bf16.h>

#define NN 100000
#define EE 1250000
#define DD 64
#define GG 256
#define COARSE 1024
#define NC ((NN + COARSE - 1) / COARSE)     // 98 coarse buckets
#define CHUNK 2048
#define NCHUNK ((EE + CHUNK - 1) / CHUNK)   // 611

static __device__ __forceinline__ float relu_f(float x) { return fmaxf(x, 0.0f); }

static __device__ __forceinline__ float b2f(ushort u) {
    return __uint_as_float(((unsigned int)u) << 16);
}
static __device__ __forceinline__ ushort f2b(float f) {
    __hip_bfloat16 h = __float2bfloat16(f);  // RNE
    return *(ushort*)&h;
}

// ---------------- coarse histogram (LDS pre-aggregated) ----------------
__global__ __launch_bounds__(256) void hist2_kernel(const int* __restrict__ dst,
                                                    int* __restrict__ ghist, int E) {
    __shared__ int h[NC];
    int t = threadIdx.x;
    if (t < NC) h[t] = 0;
    __syncthreads();
    for (int e = blockIdx.x * blockDim.x + t; e < E; e += gridDim.x * blockDim.x)
        atomicAdd(&h[dst[e] >> 10], 1);
    __syncthreads();
    if (t < NC && h[t]) atomicAdd(&ghist[t], h[t]);
}

// tiny scan over NC=98
__global__ void scan2_kernel(const int* __restrict__ ghist, int* __restrict__ coffs,
                             int* __restrict__ gcursor) {
    if (threadIdx.x == 0) {
        int run = 0;
        for (int b = 0; b < NC; b++) {
            coffs[b] = run;
            gcursor[b] = run;
            run += ghist[b];
        }
        coffs[NC] = run;
    }
}

// ---------------- LDS-binned scatter: coalesced bucket-run writes ----------------
// pack = src (17b) | dstLocal (10b) << 17
__global__ __launch_bounds__(256) void bin_kernel(
    const int* __restrict__ ei, int* __restrict__ gcursor, int* __restrict__ epack, int E) {
    __shared__ int hist[NC];
    __shared__ int base[NC];
    __shared__ int lpre[NC];
    __shared__ int scnt;
    __shared__ int lbuf[CHUNK];
    __shared__ int lobuf[CHUNK];
    int t = threadIdx.x;
    for (int c = blockIdx.x; c < NCHUNK; c += gridDim.x) {
        int e0 = c * CHUNK;
        if (t < NC) hist[t] = 0;
        __syncthreads();
        int myb[8], myloc[8], mypack[8];
#pragma unroll
        for (int q = 0; q < 8; q++) {
            int e = e0 + q * 256 + t;
            if (e < E) {
                int d = ei[E + e];
                int s = ei[e];
                int b = d >> 10;
                myb[q] = b;
                mypack[q] = s | ((d & (COARSE - 1)) << 17);
                myloc[q] = atomicAdd(&hist[b], 1);
            } else myb[q] = -1;
        }
        __syncthreads();
        if (t < NC) base[t] = hist[t] ? atomicAdd(&gcursor[t], hist[t]) : 0;
        if (t == 0) {
            int run = 0;
            for (int b = 0; b < NC; b++) { lpre[b] = run; run += hist[b]; }
            scnt = run;
        }
        __syncthreads();
#pragma unroll
        for (int q = 0; q < 8; q++) {
            if (myb[q] >= 0) {
                int p = lpre[myb[q]] + myloc[q];
                lbuf[p] = mypack[q];
                lobuf[p] = base[myb[q]] + myloc[q];
            }
        }
        __syncthreads();
        int cnt = scnt;
#pragma unroll
        for (int q = 0; q < 8; q++) {
            int p = q * 256 + t;
            if (p < cnt) epack[lobuf[p]] = lbuf[p];   // consecutive p -> consecutive dest
        }
        __syncthreads();
    }
}

// ---------------- per-coarse-bucket exact CSR build (block-private window) ------
__global__ __launch_bounds__(256) void csr2_kernel(
    const int* __restrict__ epack, const int* __restrict__ coffs,
    int* __restrict__ srcs, int* __restrict__ off) {
    __shared__ int hist[COARSE];   // counts -> then cursors
    __shared__ int tmp[256];
    int b = blockIdx.x;
    int t = threadIdx.x;
    int c0 = coffs[b], c1 = coffs[b + 1];
    int nbase = b * COARSE;
#pragma unroll
    for (int j = 0; j < 4; j++) hist[t * 4 + j] = 0;
    __syncthreads();
    for (int e = c0 + t; e < c1; e += 256)
        atomicAdd(&hist[epack[e] >> 17], 1);
    __syncthreads();
    int h0 = hist[t * 4], h1 = hist[t * 4 + 1], h2 = hist[t * 4 + 2], h3 = hist[t * 4 + 3];
    int s4 = h0 + h1 + h2 + h3;
    tmp[t] = s4;
    __syncthreads();
    for (int d = 1; d < 256; d <<= 1) {
        int v = (t >= d) ? tmp[t - d] : 0;
        __syncthreads();
        tmp[t] += v;
        __syncthreads();
    }
    int run = tmp[t] - s4;
    int pre0 = run; run += h0;
    int pre1 = run; run += h1;
    int pre2 = run; run += h2;
    int pre3 = run;
    int pres[4] = {pre0, pre1, pre2, pre3};
#pragma unroll
    for (int j = 0; j < 4; j++) {
        int node = nbase + t * 4 + j;
        if (node < NN) off[node] = c0 + pres[j];
        hist[t * 4 + j] = pres[j];   // reuse as cursor
    }
    if (b == NC - 1 && t == 0) off[NN] = c1;
    __syncthreads();
    for (int e = c0 + t; e < c1; e += 256) {
        int p = epack[e];
        int pos = c0 + atomicAdd(&hist[p >> 17], 1);
        srcs[pos] = p & 0x1FFFF;
    }
}

// graph boundaries from sorted batch
__global__ void bounds_kernel(const int* __restrict__ batch, int* __restrict__ gstart, int n) {
    int i = blockIdx.x * blockDim.x + threadIdx.x;
    if (i >= n) return;
    int b = batch[i];
    int prev = (i == 0) ? -1 : batch[i - 1];
    for (int g = prev + 1; g <= b; g++) gstart[g] = i;
    if (i == n - 1) {
        for (int g = b + 1; g <= GG; g++) gstart[g] = n;
    }
}

// fp32 -> bf16 cast of x (once)
__global__ __launch_bounds__(256) void cast_kernel(const float* __restrict__ x,
                                                   ushort* __restrict__ xb) {
    size_t i = ((size_t)blockIdx.x * blockDim.x + threadIdx.x) * 4;
    if (i >= (size_t)NN * DD) return;
    float4 v = *(const float4*)(x + i);
    ushort4 r;
    r.x = f2b(v.x); r.y = f2b(v.y); r.z = f2b(v.z); r.w = f2b(v.w);
    *(ushort4*)(xb + i) = r;
}

// ---------------- aggregation: wave per node, bf16 gather, 8-deep unroll ------
// Round-11 proven local optimum (46.7us). r13 split-wave: 52.5; r14 16-deep:
// 64.3; r15 fused-into-mlp: 110. Do not re-probe this structure.
__global__ __launch_bounds__(256) void agg_kernel(
    const ushort* __restrict__ xb, float* __restrict__ u,
    const int* __restrict__ off, const int* __restrict__ srcs, int n) {
    int node = blockIdx.x * 4 + (threadIdx.x >> 6);
    int lane = threadIdx.x & 63;
    if (node >= n) return;
    int o = off[node];
    int oe = off[node + 1];
    float a0 = b2f(xb[(size_t)node * DD + lane]);   // self
    float a1 = 0.0f, a2 = 0.0f, a3 = 0.0f, a4 = 0.0f, a5 = 0.0f, a6 = 0.0f, a7 = 0.0f;
    int j = o;
    for (; j + 8 <= oe; j += 8) {
        int s0 = srcs[j + 0], s1 = srcs[j + 1], s2 = srcs[j + 2], s3 = srcs[j + 3];
        int s4 = srcs[j + 4], s5 = srcs[j + 5], s6 = srcs[j + 6], s7 = srcs[j + 7];
        ushort v0 = xb[(size_t)s0 * DD + lane];
        ushort v1 = xb[(size_t)s1 * DD + lane];
        ushort v2 = xb[(size_t)s2 * DD + lane];
        ushort v3 = xb[(size_t)s3 * DD + lane];
        ushort v4 = xb[(size_t)s4 * DD + lane];
        ushort v5 = xb[(size_t)s5 * DD + lane];
        ushort v6 = xb[(size_t)s6 * DD + lane];
        ushort v7 = xb[(size_t)s7 * DD + lane];
        a0 += b2f(v0); a1 += b2f(v1); a2 += b2f(v2); a3 += b2f(v3);
        a4 += b2f(v4); a5 += b2f(v5); a6 += b2f(v6); a7 += b2f(v7);
    }
    for (; j + 4 <= oe; j += 4) {
        int s0 = srcs[j + 0], s1 = srcs[j + 1], s2 = srcs[j + 2], s3 = srcs[j + 3];
        ushort v0 = xb[(size_t)s0 * DD + lane];
        ushort v1 = xb[(size_t)s1 * DD + lane];
        ushort v2 = xb[(size_t)s2 * DD + lane];
        ushort v3 = xb[(size_t)s3 * DD + lane];
        a0 += b2f(v0); a1 += b2f(v1); a2 += b2f(v2); a3 += b2f(v3);
    }
    for (; j < oe; j++) a0 += b2f(xb[(size_t)srcs[j] * DD + lane]);
    u[(size_t)node * DD + lane] = ((a0 + a1) + (a2 + a3)) + ((a4 + a5) + (a6 + a7));
}

// ---------------- per-layer: block-tiled fp32 GEMM MLP (round-10 proven) ----
template <bool HAS_BN, bool OUT_BF16>
__global__ __launch_bounds__(256) void mlp_kernel(
    const float* __restrict__ u, void* __restrict__ hout,
    const float* __restrict__ wa, const float* __restrict__ ba,
    const float* __restrict__ wb, const float* __restrict__ bb,
    const float* __restrict__ bng, const float* __restrict__ bnb,
    const float* __restrict__ bnm, const float* __restrict__ bnv, int n) {
    __shared__ float At[DD][68];   // A^T: At[k][i], 68-pad keeps rows 16B-aligned
    __shared__ float Wt[DD * DD];  // W[k][j] row-major
    int t = threadIdx.x;
    int r0 = blockIdx.x * DD;
    int tx = t & 15, ty = t >> 4;
    int i0 = tx * 4, j0 = ty * 4;

    {
        int ii = t >> 2;
        int cb = (t & 3) * 16;
        int row = r0 + ii;
        if (row < n) {
            const float4* ur = (const float4*)(u + (size_t)row * DD + cb);
            float4 v0 = ur[0], v1 = ur[1], v2 = ur[2], v3 = ur[3];
            At[cb + 0][ii] = v0.x;  At[cb + 1][ii] = v0.y;
            At[cb + 2][ii] = v0.z;  At[cb + 3][ii] = v0.w;
            At[cb + 4][ii] = v1.x;  At[cb + 5][ii] = v1.y;
            At[cb + 6][ii] = v1.z;  At[cb + 7][ii] = v1.w;
            At[cb + 8][ii] = v2.x;  At[cb + 9][ii] = v2.y;
            At[cb + 10][ii] = v2.z; At[cb + 11][ii] = v2.w;
            At[cb + 12][ii] = v3.x; At[cb + 13][ii] = v3.y;
            At[cb + 14][ii] = v3.z; At[cb + 15][ii] = v3.w;
        } else {
#pragma unroll
            for (int q = 0; q < 16; q++) At[cb + q][ii] = 0.0f;
        }
#pragma unroll
        for (int rep = 0; rep < 4; rep++) {
            int idx = rep * 1024 + t * 4;
            *(float4*)&Wt[idx] = *(const float4*)&wa[idx];
        }
    }
    __syncthreads();

    float acc[4][4];
#pragma unroll
    for (int a = 0; a < 4; a++)
#pragma unroll
        for (int b = 0; b < 4; b++) acc[a][b] = 0.0f;
#pragma unroll 4
    for (int k = 0; k < DD; k++) {
        float4 av = *(const float4*)&At[k][i0];
        float4 wv = *(const float4*)&Wt[k * DD + j0];
        float aa[4] = {av.x, av.y, av.z, av.w};
        float ww[4] = {wv.x, wv.y, wv.z, wv.w};
#pragma unroll
        for (int di = 0; di < 4; di++)
#pragma unroll
            for (int dj = 0; dj < 4; dj++)
                acc[di][dj] = fmaf(aa[di], ww[dj], acc[di][dj]);
    }
    float4 ba4 = *(const float4*)&ba[j0];
    float bav[4] = {ba4.x, ba4.y, ba4.z, ba4.w};
    __syncthreads();

#pragma unroll
    for (int dj = 0; dj < 4; dj++) {
        float4 w;
        w.x = relu_f(acc[0][dj] + bav[dj]);
        w.y = relu_f(acc[1][dj] + bav[dj]);
        w.z = relu_f(acc[2][dj] + bav[dj]);
        w.w = relu_f(acc[3][dj] + bav[dj]);
        *(float4*)&At[j0 + dj][i0] = w;
    }
#pragma unroll
    for (int rep = 0; rep < 4; rep++) {
        int idx = rep * 1024 + t * 4;
        *(float4*)&Wt[idx] = *(const float4*)&wb[idx];
    }
    __syncthreads();

    float acc2[4][4];
#pragma unroll
    for (int a = 0; a < 4; a++)
#pragma unroll
        for (int b = 0; b < 4; b++) acc2[a][b] = 0.0f;
#pragma unroll 4
    for (int k = 0; k < DD; k++) {
        float4 av = *(const float4*)&At[k][i0];
        float4 wv = *(const float4*)&Wt[k * DD + j0];
        float aa[4] = {av.x, av.y, av.z, av.w};
        float ww[4] = {wv.x, wv.y, wv.z, wv.w};
#pragma unroll
        for (int di = 0; di < 4; di++)
#pragma unroll
            for (int dj = 0; dj < 4; dj++)
                acc2[di][dj] = fmaf(aa[di], ww[dj], acc2[di][dj]);
    }

    float4 bb4 = *(const float4*)&bb[j0];
    float bbv[4] = {bb4.x, bb4.y, bb4.z, bb4.w};
    float scv[4] = {0, 0, 0, 0}, shv[4] = {0, 0, 0, 0};
    if (HAS_BN) {
        float4 g4 = *(const float4*)&bng[j0];
        float4 b4 = *(const float4*)&bnb[j0];
        float4 m4 = *(const float4*)&bnm[j0];
        float4 v4 = *(const float4*)&bnv[j0];
        float gg[4] = {g4.x, g4.y, g4.z, g4.w};
        float bbn[4] = {b4.x, b4.y, b4.z, b4.w};
        float mm[4] = {m4.x, m4.y, m4.z, m4.w};
        float vv[4] = {v4.x, v4.y, v4.z, v4.w};
#pragma unroll
        for (int c = 0; c < 4; c++) {
            scv[c] = gg[c] * rsqrtf(vv[c] + 1e-5f);
            shv[c] = bbn[c] - mm[c] * scv[c];
        }
    }
#pragma unroll
    for (int di = 0; di < 4; di++) {
        int row = r0 + i0 + di;
        if (row >= n) break;
        float v[4];
#pragma unroll
        for (int dj = 0; dj < 4; dj++) {
            float tv = relu_f(acc2[di][dj] + bbv[dj]);
            if (HAS_BN) tv = fmaf(tv, scv[dj], shv[dj]);
            v[dj] = tv;
        }
        if (OUT_BF16) {
            ushort4 r;
            r.x = f2b(v[0]); r.y = f2b(v[1]); r.z = f2b(v[2]); r.w = f2b(v[3]);
            *(ushort4*)((ushort*)hout + (size_t)row * DD + j0) = r;
        } else {
            float4 r; r.x = v[0]; r.y = v[1]; r.z = v[2]; r.w = v[3];
            *(float4*)((float*)hout + (size_t)row * DD + j0) = r;
        }
    }
}

// ---------------- fused pooling + head: one block per graph (r15 validated) --
__global__ __launch_bounds__(256) void poolhead_kernel(
    const float* __restrict__ h, const int* __restrict__ gstart,
    const float* __restrict__ wp1, const float* __restrict__ bp1,
    const float* __restrict__ wp2, const float* __restrict__ bp2,
    float* __restrict__ out) {
    __shared__ float ssum[4][DD];
    __shared__ float smax[4][DD];
    __shared__ float gx[2 * DD];
    int g = blockIdx.x;
    int lane = threadIdx.x & 63;
    int wave = threadIdx.x >> 6;
    int s = gstart[g], e = gstart[g + 1];
    float sum = 0.0f, mx = 0.0f;  // layer-2 out is post-ReLU >= 0; 0 == empty-graph guard
    for (int i = s + wave; i < e; i += 4) {
        float v = h[(size_t)i * DD + lane];
        sum += v;
        mx = fmaxf(mx, v);
    }
    ssum[wave][lane] = sum;
    smax[wave][lane] = mx;
    __syncthreads();
    if (wave == 0) {
        sum = ssum[0][lane] + ssum[1][lane] + ssum[2][lane] + ssum[3][lane];
        mx = fmaxf(fmaxf(smax[0][lane], smax[1][lane]),
                   fmaxf(smax[2][lane], smax[3][lane]));
        float cnt = fmaxf((float)(e - s), 1.0f);
        gx[lane] = sum / cnt;
        gx[DD + lane] = mx;
    }
    __syncthreads();
    if (wave == 0) {
        float tt = bp1[lane];
        for (int k = 0; k < 2 * DD; k++) tt = fmaf(gx[k], wp1[k * DD + lane], tt);
        float p0 = tt * wp2[lane * 2 + 0];
        float p1 = tt * wp2[lane * 2 + 1];
        for (int o = 32; o > 0; o >>= 1) {
            p0 += __shfl_down(p0, o);
            p1 += __shfl_down(p1, o);
        }
        if (lane == 0) {
            p0 += bp2[0];
            p1 += bp2[1];
            float m = fmaxf(p0, p1);
            float lse = m + logf(expf(p0 - m) + expf(p1 - m));
            out[g * 2 + 0] = p0 - lse;
            out[g * 2 + 1] = p1 - lse;
        }
    }
}

// ---------------- launch ----------------
extern "C" void kernel_launch(void* const* d_in, const int* in_sizes, int n_in,
                              void* d_out, int out_size, void* d_ws, size_t ws_size,
                              hipStream_t stream) {
    const float* x     = (const float*)d_in[0];
    const int*   ei    = (const int*)d_in[1];
    const int*   batch = (const int*)d_in[2];
    const float* w0a = (const float*)d_in[3];  const float* b0a = (const float*)d_in[4];
    const float* w0b = (const float*)d_in[5];  const float* b0b = (const float*)d_in[6];
    const float* w1a = (const float*)d_in[7];  const float* b1a = (const float*)d_in[8];
    const float* w1b = (const float*)d_in[9];  const float* b1b = (const float*)d_in[10];
    const float* w2a = (const float*)d_in[11]; const float* b2a = (const float*)d_in[12];
    const float* w2b = (const float*)d_in[13]; const float* b2b = (const float*)d_in[14];
    const float* bn0g = (const float*)d_in[15]; const float* bn0b = (const float*)d_in[16];
    const float* bn0m = (const float*)d_in[17]; const float* bn0v = (const float*)d_in[18];
    const float* bn1g = (const float*)d_in[19]; const float* bn1b = (const float*)d_in[20];
    const float* bn1m = (const float*)d_in[21]; const float* bn1v = (const float*)d_in[22];
    const float* wp1 = (const float*)d_in[23]; const float* bp1 = (const float*)d_in[24];
    const float* wp2 = (const float*)d_in[25]; const float* bp2 = (const float*)d_in[26];
    float* out = (float*)d_out;

    char* p = (char*)d_ws;
    auto take = [&](size_t bytes) {
        char* r = p;
        p += (bytes + 255) & ~(size_t)255;
        return r;
    };
    int* ghist   = (int*)take(NC * sizeof(int));
    int* coffs   = (int*)take((NC + 1) * sizeof(int));
    int* gcursor = (int*)take(NC * sizeof(int));
    int* epack   = (int*)take(EE * sizeof(int));
    int* srcs    = (int*)take(EE * sizeof(int));
    int* off     = (int*)take((NN + 1) * sizeof(int));
    int* gstart  = (int*)take((GG + 1) * sizeof(int));
    ushort* xb   = (ushort*)take((size_t)NN * DD * sizeof(ushort));
    float* bufU  = (float*)take((size_t)NN * DD * sizeof(float));
    ushort* hA   = (ushort*)take((size_t)NN * DD * sizeof(ushort));
    ushort* hB   = (ushort*)take((size_t)NN * DD * sizeof(ushort));
    float* hC    = (float*)take((size_t)NN * DD * sizeof(float));

    // CSR build: coarse hist -> scan -> LDS-binned scatter -> per-bucket CSR
    hipMemsetAsync(ghist, 0, NC * sizeof(int), stream);
    hist2_kernel<<<512, 256, 0, stream>>>(ei + EE, ghist, EE);
    scan2_kernel<<<1, 64, 0, stream>>>(ghist, coffs, gcursor);
    bin_kernel<<<512, 256, 0, stream>>>(ei, gcursor, epack, EE);
    csr2_kernel<<<NC, 256, 0, stream>>>(epack, coffs, srcs, off);
    bounds_kernel<<<(NN + 255) / 256, 256, 0, stream>>>(batch, gstart, NN);
    cast_kernel<<<(NN * DD / 4 + 255) / 256, 256, 0, stream>>>(x, xb);

    int agg_grid = (NN + 3) / 4;
    int mlp_grid = (NN + DD - 1) / DD;   // 1563 blocks of 64 nodes

    // layer 0
    agg_kernel<<<agg_grid, 256, 0, stream>>>(xb, bufU, off, srcs, NN);
    mlp_kernel<true, true><<<mlp_grid, 256, 0, stream>>>(bufU, hA, w0a, b0a, w0b, b0b,
                                                         bn0g, bn0b, bn0m, bn0v, NN);
    // layer 1
    agg_kernel<<<agg_grid, 256, 0, stream>>>(hA, bufU, off, srcs, NN);
    mlp_kernel<true, true><<<mlp_grid, 256, 0, stream>>>(bufU, hB, w1a, b1a, w1b, b1b,
                                                         bn1g, bn1b, bn1m, bn1v, NN);
    // layer 2 (fp32 out)
    agg_kernel<<<agg_grid, 256, 0, stream>>>(hB, bufU, off, srcs, NN);
    mlp_kernel<false, false><<<mlp_grid, 256, 0, stream>>>(bufU, hC, w2a, b2a, w2b, b2b,
                                                           nullptr, nullptr, nullptr, nullptr, NN);

    // fused pooling + head
    poolhead_kernel<<<GG, 256, 0, stream>>>(hC, gstart, wp1, bp1, wp2, bp2, out);
}

// Round 19
// 310.108 us; speedup vs baseline: 1.3962x; 1.1007x over previous
//
#include <hip/hip_runtime.h>
#include <hip/hip_bf16.h>

#define NN 100000
#define EE 1250000
#define DD 64
#define GG 256
#define COARSE 1024
#define NC ((NN + COARSE - 1) / COARSE)     // 98 coarse buckets
#define CHUNK 2048
#define NCHUNK ((EE + CHUNK - 1) / CHUNK)   // 611
#define PAD 72                              // bf16 row pad: 144B rows, 16B-aligned

typedef short bf8_t __attribute__((ext_vector_type(8)));   // 8 bf16
typedef float f4_t __attribute__((ext_vector_type(4)));

static __device__ __forceinline__ float relu_f(float x) { return fmaxf(x, 0.0f); }

static __device__ __forceinline__ float b2f(ushort u) {
    return __uint_as_float(((unsigned int)u) << 16);
}
static __device__ __forceinline__ ushort f2b(float f) {
    __hip_bfloat16 h = __float2bfloat16(f);  // RNE
    return *(ushort*)&h;
}

// ---------------- coarse histogram (LDS pre-aggregated) ----------------
__global__ __launch_bounds__(256) void hist2_kernel(const int* __restrict__ dst,
                                                    int* __restrict__ ghist, int E) {
    __shared__ int h[NC];
    int t = threadIdx.x;
    if (t < NC) h[t] = 0;
    __syncthreads();
    for (int e = blockIdx.x * blockDim.x + t; e < E; e += gridDim.x * blockDim.x)
        atomicAdd(&h[dst[e] >> 10], 1);
    __syncthreads();
    if (t < NC && h[t]) atomicAdd(&ghist[t], h[t]);
}

// tiny scan over NC=98
__global__ void scan2_kernel(const int* __restrict__ ghist, int* __restrict__ coffs,
                             int* __restrict__ gcursor) {
    if (threadIdx.x == 0) {
        int run = 0;
        for (int b = 0; b < NC; b++) {
            coffs[b] = run;
            gcursor[b] = run;
            run += ghist[b];
        }
        coffs[NC] = run;
    }
}

// ---------------- LDS-binned scatter: coalesced bucket-run writes ----------------
// pack = src (17b) | dstLocal (10b) << 17
__global__ __launch_bounds__(256) void bin_kernel(
    const int* __restrict__ ei, int* __restrict__ gcursor, int* __restrict__ epack, int E) {
    __shared__ int hist[NC];
    __shared__ int base[NC];
    __shared__ int lpre[NC];
    __shared__ int scnt;
    __shared__ int lbuf[CHUNK];
    __shared__ int lobuf[CHUNK];
    int t = threadIdx.x;
    for (int c = blockIdx.x; c < NCHUNK; c += gridDim.x) {
        int e0 = c * CHUNK;
        if (t < NC) hist[t] = 0;
        __syncthreads();
        int myb[8], myloc[8], mypack[8];
#pragma unroll
        for (int q = 0; q < 8; q++) {
            int e = e0 + q * 256 + t;
            if (e < E) {
                int d = ei[E + e];
                int s = ei[e];
                int b = d >> 10;
                myb[q] = b;
                mypack[q] = s | ((d & (COARSE - 1)) << 17);
                myloc[q] = atomicAdd(&hist[b], 1);
            } else myb[q] = -1;
        }
        __syncthreads();
        if (t < NC) base[t] = hist[t] ? atomicAdd(&gcursor[t], hist[t]) : 0;
        if (t == 0) {
            int run = 0;
            for (int b = 0; b < NC; b++) { lpre[b] = run; run += hist[b]; }
            scnt = run;
        }
        __syncthreads();
#pragma unroll
        for (int q = 0; q < 8; q++) {
            if (myb[q] >= 0) {
                int p = lpre[myb[q]] + myloc[q];
                lbuf[p] = mypack[q];
                lobuf[p] = base[myb[q]] + myloc[q];
            }
        }
        __syncthreads();
        int cnt = scnt;
#pragma unroll
        for (int q = 0; q < 8; q++) {
            int p = q * 256 + t;
            if (p < cnt) epack[lobuf[p]] = lbuf[p];   // consecutive p -> consecutive dest
        }
        __syncthreads();
    }
}

// ---------------- per-coarse-bucket exact CSR build (block-private window) ------
__global__ __launch_bounds__(256) void csr2_kernel(
    const int* __restrict__ epack, const int* __restrict__ coffs,
    int* __restrict__ srcs, int* __restrict__ off) {
    __shared__ int hist[COARSE];   // counts -> then cursors
    __shared__ int tmp[256];
    int b = blockIdx.x;
    int t = threadIdx.x;
    int c0 = coffs[b], c1 = coffs[b + 1];
    int nbase = b * COARSE;
#pragma unroll
    for (int j = 0; j < 4; j++) hist[t * 4 + j] = 0;
    __syncthreads();
    for (int e = c0 + t; e < c1; e += 256)
        atomicAdd(&hist[epack[e] >> 17], 1);
    __syncthreads();
    int h0 = hist[t * 4], h1 = hist[t * 4 + 1], h2 = hist[t * 4 + 2], h3 = hist[t * 4 + 3];
    int s4 = h0 + h1 + h2 + h3;
    tmp[t] = s4;
    __syncthreads();
    for (int d = 1; d < 256; d <<= 1) {
        int v = (t >= d) ? tmp[t - d] : 0;
        __syncthreads();
        tmp[t] += v;
        __syncthreads();
    }
    int run = tmp[t] - s4;
    int pre0 = run; run += h0;
    int pre1 = run; run += h1;
    int pre2 = run; run += h2;
    int pre3 = run;
    int pres[4] = {pre0, pre1, pre2, pre3};
#pragma unroll
    for (int j = 0; j < 4; j++) {
        int node = nbase + t * 4 + j;
        if (node < NN) off[node] = c0 + pres[j];
        hist[t * 4 + j] = pres[j];   // reuse as cursor
    }
    if (b == NC - 1 && t == 0) off[NN] = c1;
    __syncthreads();
    for (int e = c0 + t; e < c1; e += 256) {
        int p = epack[e];
        int pos = c0 + atomicAdd(&hist[p >> 17], 1);
        srcs[pos] = p & 0x1FFFF;
    }
}

// graph boundaries from sorted batch
__global__ void bounds_kernel(const int* __restrict__ batch, int* __restrict__ gstart, int n) {
    int i = blockIdx.x * blockDim.x + threadIdx.x;
    if (i >= n) return;
    int b = batch[i];
    int prev = (i == 0) ? -1 : batch[i - 1];
    for (int g = prev + 1; g <= b; g++) gstart[g] = i;
    if (i == n - 1) {
        for (int g = b + 1; g <= GG; g++) gstart[g] = n;
    }
}

// fp32 -> bf16 cast of x (once)
__global__ __launch_bounds__(256) void cast_kernel(const float* __restrict__ x,
                                                   ushort* __restrict__ xb) {
    size_t i = ((size_t)blockIdx.x * blockDim.x + threadIdx.x) * 4;
    if (i >= (size_t)NN * DD) return;
    float4 v = *(const float4*)(x + i);
    ushort4 r;
    r.x = f2b(v.x); r.y = f2b(v.y); r.z = f2b(v.z); r.w = f2b(v.w);
    *(ushort4*)(xb + i) = r;
}

// weights: fp32 [k][n] -> bf16 hi+lo [n][k] (once; one block per matrix)
__global__ __launch_bounds__(256) void prepw_kernel(
    const float* __restrict__ w0a, const float* __restrict__ w0b,
    const float* __restrict__ w1a, const float* __restrict__ w1b,
    const float* __restrict__ w2a, const float* __restrict__ w2b,
    ushort* __restrict__ wt) {
    const float* srcs_[6] = {w0a, w0b, w1a, w1b, w2a, w2b};
    const float* src = srcs_[blockIdx.x];
    ushort* dhi = wt + (size_t)(2 * blockIdx.x) * DD * DD;
    ushort* dlo = wt + (size_t)(2 * blockIdx.x + 1) * DD * DD;
    int t = threadIdx.x;
    int nn = t >> 2, kseg = (t & 3) * 16;
    ushort thi[16], tlo[16];
#pragma unroll
    for (int q = 0; q < 16; q++) {
        float v = src[(size_t)(kseg + q) * DD + nn];
        ushort hh = f2b(v);
        thi[q] = hh;
        tlo[q] = f2b(v - b2f(hh));
    }
    *(uint4*)&dhi[nn * DD + kseg] = *(uint4*)&thi[0];
    *(uint4*)&dhi[nn * DD + kseg + 8] = *(uint4*)&thi[8];
    *(uint4*)&dlo[nn * DD + kseg] = *(uint4*)&tlo[0];
    *(uint4*)&dlo[nn * DD + kseg + 8] = *(uint4*)&tlo[8];
}

// ---------------- aggregation: wave per node, bf16 gather, 8-deep unroll ------
// Round-11 proven local optimum (46.7us). Do not re-probe this structure.
__global__ __launch_bounds__(256) void agg_kernel(
    const ushort* __restrict__ xb, float* __restrict__ u,
    const int* __restrict__ off, const int* __restrict__ srcs, int n) {
    int node = blockIdx.x * 4 + (threadIdx.x >> 6);
    int lane = threadIdx.x & 63;
    if (node >= n) return;
    int o = off[node];
    int oe = off[node + 1];
    float a0 = b2f(xb[(size_t)node * DD + lane]);   // self
    float a1 = 0.0f, a2 = 0.0f, a3 = 0.0f, a4 = 0.0f, a5 = 0.0f, a6 = 0.0f, a7 = 0.0f;
    int j = o;
    for (; j + 8 <= oe; j += 8) {
        int s0 = srcs[j + 0], s1 = srcs[j + 1], s2 = srcs[j + 2], s3 = srcs[j + 3];
        int s4 = srcs[j + 4], s5 = srcs[j + 5], s6 = srcs[j + 6], s7 = srcs[j + 7];
        ushort v0 = xb[(size_t)s0 * DD + lane];
        ushort v1 = xb[(size_t)s1 * DD + lane];
        ushort v2 = xb[(size_t)s2 * DD + lane];
        ushort v3 = xb[(size_t)s3 * DD + lane];
        ushort v4 = xb[(size_t)s4 * DD + lane];
        ushort v5 = xb[(size_t)s5 * DD + lane];
        ushort v6 = xb[(size_t)s6 * DD + lane];
        ushort v7 = xb[(size_t)s7 * DD + lane];
        a0 += b2f(v0); a1 += b2f(v1); a2 += b2f(v2); a3 += b2f(v3);
        a4 += b2f(v4); a5 += b2f(v5); a6 += b2f(v6); a7 += b2f(v7);
    }
    for (; j + 4 <= oe; j += 4) {
        int s0 = srcs[j + 0], s1 = srcs[j + 1], s2 = srcs[j + 2], s3 = srcs[j + 3];
        ushort v0 = xb[(size_t)s0 * DD + lane];
        ushort v1 = xb[(size_t)s1 * DD + lane];
        ushort v2 = xb[(size_t)s2 * DD + lane];
        ushort v3 = xb[(size_t)s3 * DD + lane];
        a0 += b2f(v0); a1 += b2f(v1); a2 += b2f(v2); a3 += b2f(v3);
    }
    for (; j < oe; j++) a0 += b2f(xb[(size_t)srcs[j] * DD + lane]);
    u[(size_t)node * DD + lane] = ((a0 + a1) + (a2 + a3)) + ((a4 + a5) + (a6 + a7));
}

// ---------------- per-layer MLP via MFMA bf16, split A AND W ------------------
// r17: all-bf16 -> 0.766. r18: A hi/lo -> 0.4375 (residual = weight rounding).
// Now: D = Ah@Wh + Al@Wh + Ah@Wl (skip Al@Wl ~ 2^-16 rel) ~= fp32 accuracy.
// Wh/Wl re-staged with W2 between GEMMs -> LDS stays 36.9KB (4 blocks/CU).
// A: row=l&15, k=(l>>4)*8+j; B: col=l&15 ([n][k]); C/D: col=l&15, row=(l>>4)*4+r.
template <bool HAS_BN, bool OUT_BF16>
__global__ __launch_bounds__(256) void mlpm_kernel(
    const float* __restrict__ u, void* __restrict__ hout,
    const ushort* __restrict__ wah, const ushort* __restrict__ wal,
    const float* __restrict__ ba,
    const ushort* __restrict__ wbh, const ushort* __restrict__ wbl,
    const float* __restrict__ bb,
    const float* __restrict__ bng, const float* __restrict__ bnb,
    const float* __restrict__ bnm, const float* __restrict__ bnv, int n) {
    __shared__ ushort Ahi[DD][PAD];
    __shared__ ushort Alo[DD][PAD];
    __shared__ ushort Wh[DD][PAD];
    __shared__ ushort Wl[DD][PAD];
    int t = threadIdx.x;
    int r0 = blockIdx.x * DD;
    int w = t >> 6, l = t & 63;
    int lr = l & 15, lg = l >> 4;
    int srow = t >> 2, sseg = t & 3;   // staging coords

    // stage A (u -> hi/lo bf16) + W1 hi/lo
    {
        int grow = r0 + srow;
        ushort thi[16], tlo[16];
        if (grow < n) {
            const float4* up = (const float4*)(u + (size_t)grow * DD + sseg * 16);
#pragma unroll
            for (int q = 0; q < 4; q++) {
                float4 v = up[q];
                float vv[4] = {v.x, v.y, v.z, v.w};
#pragma unroll
                for (int c = 0; c < 4; c++) {
                    ushort hh = f2b(vv[c]);
                    thi[q * 4 + c] = hh;
                    tlo[q * 4 + c] = f2b(vv[c] - b2f(hh));
                }
            }
        } else {
#pragma unroll
            for (int q = 0; q < 16; q++) { thi[q] = 0; tlo[q] = 0; }
        }
        *(uint4*)&Ahi[srow][sseg * 16] = *(uint4*)&thi[0];
        *(uint4*)&Ahi[srow][sseg * 16 + 8] = *(uint4*)&thi[8];
        *(uint4*)&Alo[srow][sseg * 16] = *(uint4*)&tlo[0];
        *(uint4*)&Alo[srow][sseg * 16 + 8] = *(uint4*)&tlo[8];
        const uint4* whp = (const uint4*)(wah + srow * DD + sseg * 16);
        *(uint4*)&Wh[srow][sseg * 16] = whp[0];
        *(uint4*)&Wh[srow][sseg * 16 + 8] = whp[1];
        const uint4* wlp = (const uint4*)(wal + srow * DD + sseg * 16);
        *(uint4*)&Wl[srow][sseg * 16] = wlp[0];
        *(uint4*)&Wl[srow][sseg * 16 + 8] = wlp[1];
    }
    __syncthreads();

    // GEMM1: z1 = relu((Ah+Al)@(Wh+Wl) + ba), dropping Al@Wl
    f4_t acc[4];
#pragma unroll
    for (int nt = 0; nt < 4; nt++) acc[nt] = (f4_t){0.0f, 0.0f, 0.0f, 0.0f};
#pragma unroll
    for (int ks = 0; ks < 2; ks++) {
        bf8_t ah = *(const bf8_t*)&Ahi[w * 16 + lr][ks * 32 + lg * 8];
        bf8_t al = *(const bf8_t*)&Alo[w * 16 + lr][ks * 32 + lg * 8];
#pragma unroll
        for (int nt = 0; nt < 4; nt++) {
            bf8_t bh = *(const bf8_t*)&Wh[nt * 16 + lr][ks * 32 + lg * 8];
            bf8_t bl = *(const bf8_t*)&Wl[nt * 16 + lr][ks * 32 + lg * 8];
            acc[nt] = __builtin_amdgcn_mfma_f32_16x16x32_bf16(ah, bh, acc[nt], 0, 0, 0);
            acc[nt] = __builtin_amdgcn_mfma_f32_16x16x32_bf16(al, bh, acc[nt], 0, 0, 0);
            acc[nt] = __builtin_amdgcn_mfma_f32_16x16x32_bf16(ah, bl, acc[nt], 0, 0, 0);
        }
    }
    // z1 hi/lo -> alias into Ahi/Alo (wave-own rows only)
#pragma unroll
    for (int nt = 0; nt < 4; nt++) {
        float bav = ba[nt * 16 + lr];
#pragma unroll
        for (int r = 0; r < 4; r++) {
            float z = relu_f(acc[nt][r] + bav);
            ushort zh = f2b(z);
            Ahi[w * 16 + lg * 4 + r][nt * 16 + lr] = zh;
            Alo[w * 16 + lg * 4 + r][nt * 16 + lr] = f2b(z - b2f(zh));
        }
    }
    __syncthreads();   // GEMM1 W-reads + Z-writes complete

    // re-stage Wh/Wl with W2
    {
        const uint4* whp = (const uint4*)(wbh + srow * DD + sseg * 16);
        *(uint4*)&Wh[srow][sseg * 16] = whp[0];
        *(uint4*)&Wh[srow][sseg * 16 + 8] = whp[1];
        const uint4* wlp = (const uint4*)(wbl + srow * DD + sseg * 16);
        *(uint4*)&Wl[srow][sseg * 16] = wlp[0];
        *(uint4*)&Wl[srow][sseg * 16 + 8] = wlp[1];
    }
    __syncthreads();

    // GEMM2: z2 = (Zh+Zl)@(Wh+Wl), dropping Zl@Wl
    f4_t acc2[4];
#pragma unroll
    for (int nt = 0; nt < 4; nt++) acc2[nt] = (f4_t){0.0f, 0.0f, 0.0f, 0.0f};
#pragma unroll
    for (int ks = 0; ks < 2; ks++) {
        bf8_t ah = *(const bf8_t*)&Ahi[w * 16 + lr][ks * 32 + lg * 8];
        bf8_t al = *(const bf8_t*)&Alo[w * 16 + lr][ks * 32 + lg * 8];
#pragma unroll
        for (int nt = 0; nt < 4; nt++) {
            bf8_t bh = *(const bf8_t*)&Wh[nt * 16 + lr][ks * 32 + lg * 8];
            bf8_t bl = *(const bf8_t*)&Wl[nt * 16 + lr][ks * 32 + lg * 8];
            acc2[nt] = __builtin_amdgcn_mfma_f32_16x16x32_bf16(ah, bh, acc2[nt], 0, 0, 0);
            acc2[nt] = __builtin_amdgcn_mfma_f32_16x16x32_bf16(al, bh, acc2[nt], 0, 0, 0);
            acc2[nt] = __builtin_amdgcn_mfma_f32_16x16x32_bf16(ah, bl, acc2[nt], 0, 0, 0);
        }
    }

    // epilogue: +bb, relu, [BN], store
#pragma unroll
    for (int nt = 0; nt < 4; nt++) {
        int col = nt * 16 + lr;
        float bbv = bb[col];
        float sc = 1.0f, sh = 0.0f;
        if (HAS_BN) {
            sc = bng[col] * rsqrtf(bnv[col] + 1e-5f);
            sh = bnb[col] - bnm[col] * sc;
        }
#pragma unroll
        for (int r = 0; r < 4; r++) {
            int row = r0 + w * 16 + lg * 4 + r;
            if (row < n) {
                float v = relu_f(acc2[nt][r] + bbv);
                if (HAS_BN) v = fmaf(v, sc, sh);
                if (OUT_BF16) ((ushort*)hout)[(size_t)row * DD + col] = f2b(v);
                else ((float*)hout)[(size_t)row * DD + col] = v;
            }
        }
    }
}

// ---------------- fused pooling + head: one block per graph (r15 validated) --
__global__ __launch_bounds__(256) void poolhead_kernel(
    const float* __restrict__ h, const int* __restrict__ gstart,
    const float* __restrict__ wp1, const float* __restrict__ bp1,
    const float* __restrict__ wp2, const float* __restrict__ bp2,
    float* __restrict__ out) {
    __shared__ float ssum[4][DD];
    __shared__ float smax[4][DD];
    __shared__ float gx[2 * DD];
    int g = blockIdx.x;
    int lane = threadIdx.x & 63;
    int wave = threadIdx.x >> 6;
    int s = gstart[g], e = gstart[g + 1];
    float sum = 0.0f, mx = 0.0f;  // layer-2 out is post-ReLU >= 0; 0 == empty-graph guard
    for (int i = s + wave; i < e; i += 4) {
        float v = h[(size_t)i * DD + lane];
        sum += v;
        mx = fmaxf(mx, v);
    }
    ssum[wave][lane] = sum;
    smax[wave][lane] = mx;
    __syncthreads();
    if (wave == 0) {
        sum = ssum[0][lane] + ssum[1][lane] + ssum[2][lane] + ssum[3][lane];
        mx = fmaxf(fmaxf(smax[0][lane], smax[1][lane]),
                   fmaxf(smax[2][lane], smax[3][lane]));
        float cnt = fmaxf((float)(e - s), 1.0f);
        gx[lane] = sum / cnt;
        gx[DD + lane] = mx;
    }
    __syncthreads();
    if (wave == 0) {
        float tt = bp1[lane];
        for (int k = 0; k < 2 * DD; k++) tt = fmaf(gx[k], wp1[k * DD + lane], tt);
        float p0 = tt * wp2[lane * 2 + 0];
        float p1 = tt * wp2[lane * 2 + 1];
        for (int o = 32; o > 0; o >>= 1) {
            p0 += __shfl_down(p0, o);
            p1 += __shfl_down(p1, o);
        }
        if (lane == 0) {
            p0 += bp2[0];
            p1 += bp2[1];
            float m = fmaxf(p0, p1);
            float lse = m + logf(expf(p0 - m) + expf(p1 - m));
            out[g * 2 + 0] = p0 - lse;
            out[g * 2 + 1] = p1 - lse;
        }
    }
}

// ---------------- launch ----------------
extern "C" void kernel_launch(void* const* d_in, const int* in_sizes, int n_in,
                              void* d_out, int out_size, void* d_ws, size_t ws_size,
                              hipStream_t stream) {
    const float* x     = (const float*)d_in[0];
    const int*   ei    = (const int*)d_in[1];
    const int*   batch = (const int*)d_in[2];
    const float* w0a = (const float*)d_in[3];  const float* b0a = (const float*)d_in[4];
    const float* w0b = (const float*)d_in[5];  const float* b0b = (const float*)d_in[6];
    const float* w1a = (const float*)d_in[7];  const float* b1a = (const float*)d_in[8];
    const float* w1b = (const float*)d_in[9];  const float* b1b = (const float*)d_in[10];
    const float* w2a = (const float*)d_in[11]; const float* b2a = (const float*)d_in[12];
    const float* w2b = (const float*)d_in[13]; const float* b2b = (const float*)d_in[14];
    const float* bn0g = (const float*)d_in[15]; const float* bn0b = (const float*)d_in[16];
    const float* bn0m = (const float*)d_in[17]; const float* bn0v = (const float*)d_in[18];
    const float* bn1g = (const float*)d_in[19]; const float* bn1b = (const float*)d_in[20];
    const float* bn1m = (const float*)d_in[21]; const float* bn1v = (const float*)d_in[22];
    const float* wp1 = (const float*)d_in[23]; const float* bp1 = (const float*)d_in[24];
    const float* wp2 = (const float*)d_in[25]; const float* bp2 = (const float*)d_in[26];
    float* out = (float*)d_out;

    char* p = (char*)d_ws;
    auto take = [&](size_t bytes) {
        char* r = p;
        p += (bytes + 255) & ~(size_t)255;
        return r;
    };
    int* ghist   = (int*)take(NC * sizeof(int));
    int* coffs   = (int*)take((NC + 1) * sizeof(int));
    int* gcursor = (int*)take(NC * sizeof(int));
    int* epack   = (int*)take(EE * sizeof(int));
    int* srcs    = (int*)take(EE * sizeof(int));
    int* off     = (int*)take((NN + 1) * sizeof(int));
    int* gstart  = (int*)take((GG + 1) * sizeof(int));
    ushort* xb   = (ushort*)take((size_t)NN * DD * sizeof(ushort));
    float* bufU  = (float*)take((size_t)NN * DD * sizeof(float));
    ushort* hA   = (ushort*)take((size_t)NN * DD * sizeof(ushort));
    ushort* hB   = (ushort*)take((size_t)NN * DD * sizeof(ushort));
    float* hC    = (float*)take((size_t)NN * DD * sizeof(float));
    ushort* wt   = (ushort*)take(12 * DD * DD * sizeof(ushort));   // bf16 hi/lo [n][k] x6

    // CSR build + bounds + casts + weight prep
    hipMemsetAsync(ghist, 0, NC * sizeof(int), stream);
    hist2_kernel<<<512, 256, 0, stream>>>(ei + EE, ghist, EE);
    scan2_kernel<<<1, 64, 0, stream>>>(ghist, coffs, gcursor);
    bin_kernel<<<512, 256, 0, stream>>>(ei, gcursor, epack, EE);
    csr2_kernel<<<NC, 256, 0, stream>>>(epack, coffs, srcs, off);
    bounds_kernel<<<(NN + 255) / 256, 256, 0, stream>>>(batch, gstart, NN);
    cast_kernel<<<(NN * DD / 4 + 255) / 256, 256, 0, stream>>>(x, xb);
    prepw_kernel<<<6, 256, 0, stream>>>(w0a, w0b, w1a, w1b, w2a, w2b, wt);

    int agg_grid = (NN + 3) / 4;
    int mlp_grid = (NN + DD - 1) / DD;   // 1563 blocks of 64 nodes
    const size_t M = (size_t)DD * DD;
    ushort* w0ah = wt + 0 * M;  ushort* w0al = wt + 1 * M;
    ushort* w0bh = wt + 2 * M;  ushort* w0bl = wt + 3 * M;
    ushort* w1ah = wt + 4 * M;  ushort* w1al = wt + 5 * M;
    ushort* w1bh = wt + 6 * M;  ushort* w1bl = wt + 7 * M;
    ushort* w2ah = wt + 8 * M;  ushort* w2al = wt + 9 * M;
    ushort* w2bh = wt + 10 * M; ushort* w2bl = wt + 11 * M;

    // layer 0
    agg_kernel<<<agg_grid, 256, 0, stream>>>(xb, bufU, off, srcs, NN);
    mlpm_kernel<true, true><<<mlp_grid, 256, 0, stream>>>(
        bufU, hA, w0ah, w0al, b0a, w0bh, w0bl, b0b, bn0g, bn0b, bn0m, bn0v, NN);
    // layer 1
    agg_kernel<<<agg_grid, 256, 0, stream>>>(hA, bufU, off, srcs, NN);
    mlpm_kernel<true, true><<<mlp_grid, 256, 0, stream>>>(
        bufU, hB, w1ah, w1al, b1a, w1bh, w1bl, b1b, bn1g, bn1b, bn1m, bn1v, NN);
    // layer 2 (fp32 out)
    agg_kernel<<<agg_grid, 256, 0, stream>>>(hB, bufU, off, srcs, NN);
    mlpm_kernel<false, false><<<mlp_grid, 256, 0, stream>>>(
        bufU, hC, w2ah, w2al, b2a, w2bh, w2bl, b2b, nullptr, nullptr, nullptr, nullptr, NN);

    // fused pooling + head
    poolhead_kernel<<<GG, 256, 0, stream>>>(hC, gstart, wp1, bp1, wp2, bp2, out);
}

// Round 20
// 303.340 us; speedup vs baseline: 1.4273x; 1.0223x over previous
//
#include <hip/hip_runtime.h>
#include <hip/hip_bf16.h>

#define NN 100000
#define EE 1250000
#define DD 64
#define GG 256
#define COARSE 1024
#define NC ((NN + COARSE - 1) / COARSE)     // 98 coarse buckets
#define CHUNK 2048
#define NCHUNK ((EE + CHUNK - 1) / CHUNK)   // 611
#define PAD 72                              // bf16 row pad: 144B rows, 16B-aligned

typedef short bf8_t __attribute__((ext_vector_type(8)));   // 8 bf16
typedef float f4_t __attribute__((ext_vector_type(4)));

static __device__ __forceinline__ float relu_f(float x) { return fmaxf(x, 0.0f); }

static __device__ __forceinline__ float b2f(ushort u) {
    return __uint_as_float(((unsigned int)u) << 16);
}
static __device__ __forceinline__ ushort f2b(float f) {
    __hip_bfloat16 h = __float2bfloat16(f);  // RNE
    return *(ushort*)&h;
}

// ---------------- coarse histogram (LDS pre-aggregated) ----------------
__global__ __launch_bounds__(256) void hist2_kernel(const int* __restrict__ dst,
                                                    int* __restrict__ ghist, int E) {
    __shared__ int h[NC];
    int t = threadIdx.x;
    if (t < NC) h[t] = 0;
    __syncthreads();
    for (int e = blockIdx.x * blockDim.x + t; e < E; e += gridDim.x * blockDim.x)
        atomicAdd(&h[dst[e] >> 10], 1);
    __syncthreads();
    if (t < NC && h[t]) atomicAdd(&ghist[t], h[t]);
}

// parallel scan over NC=98 (was 1-thread serial; now 1 block of 128)
__global__ __launch_bounds__(128) void scan2_kernel(
    const int* __restrict__ ghist, int* __restrict__ coffs, int* __restrict__ gcursor) {
    __shared__ int tmp[128];
    int t = threadIdx.x;
    int v = (t < NC) ? ghist[t] : 0;
    tmp[t] = v;
    __syncthreads();
    for (int d = 1; d < 128; d <<= 1) {
        int u = (t >= d) ? tmp[t - d] : 0;
        __syncthreads();
        tmp[t] += u;
        __syncthreads();
    }
    if (t < NC) {
        int excl = tmp[t] - v;
        coffs[t] = excl;
        gcursor[t] = excl;
    }
    if (t == 127) coffs[NC] = tmp[127];
}

// ---------------- LDS-binned scatter: coalesced bucket-run writes ----------------
// pack = src (17b) | dstLocal (10b) << 17
__global__ __launch_bounds__(256) void bin_kernel(
    const int* __restrict__ ei, int* __restrict__ gcursor, int* __restrict__ epack, int E) {
    __shared__ int hist[NC];
    __shared__ int base[NC];
    __shared__ int lpre[NC];
    __shared__ int scnt;
    __shared__ int lbuf[CHUNK];
    __shared__ int lobuf[CHUNK];
    int t = threadIdx.x;
    for (int c = blockIdx.x; c < NCHUNK; c += gridDim.x) {
        int e0 = c * CHUNK;
        if (t < NC) hist[t] = 0;
        __syncthreads();
        int myb[8], myloc[8], mypack[8];
#pragma unroll
        for (int q = 0; q < 8; q++) {
            int e = e0 + q * 256 + t;
            if (e < E) {
                int d = ei[E + e];
                int s = ei[e];
                int b = d >> 10;
                myb[q] = b;
                mypack[q] = s | ((d & (COARSE - 1)) << 17);
                myloc[q] = atomicAdd(&hist[b], 1);
            } else myb[q] = -1;
        }
        __syncthreads();
        if (t < NC) base[t] = hist[t] ? atomicAdd(&gcursor[t], hist[t]) : 0;
        if (t == 0) {
            int run = 0;
            for (int b = 0; b < NC; b++) { lpre[b] = run; run += hist[b]; }
            scnt = run;
        }
        __syncthreads();
#pragma unroll
        for (int q = 0; q < 8; q++) {
            if (myb[q] >= 0) {
                int p = lpre[myb[q]] + myloc[q];
                lbuf[p] = mypack[q];
                lobuf[p] = base[myb[q]] + myloc[q];
            }
        }
        __syncthreads();
        int cnt = scnt;
#pragma unroll
        for (int q = 0; q < 8; q++) {
            int p = q * 256 + t;
            if (p < cnt) epack[lobuf[p]] = lbuf[p];   // consecutive p -> consecutive dest
        }
        __syncthreads();
    }
}

// ---------------- per-coarse-bucket exact CSR build (block-private window) ------
__global__ __launch_bounds__(256) void csr2_kernel(
    const int* __restrict__ epack, const int* __restrict__ coffs,
    int* __restrict__ srcs, int* __restrict__ off) {
    __shared__ int hist[COARSE];   // counts -> then cursors
    __shared__ int tmp[256];
    int b = blockIdx.x;
    int t = threadIdx.x;
    int c0 = coffs[b], c1 = coffs[b + 1];
    int nbase = b * COARSE;
#pragma unroll
    for (int j = 0; j < 4; j++) hist[t * 4 + j] = 0;
    __syncthreads();
    for (int e = c0 + t; e < c1; e += 256)
        atomicAdd(&hist[epack[e] >> 17], 1);
    __syncthreads();
    int h0 = hist[t * 4], h1 = hist[t * 4 + 1], h2 = hist[t * 4 + 2], h3 = hist[t * 4 + 3];
    int s4 = h0 + h1 + h2 + h3;
    tmp[t] = s4;
    __syncthreads();
    for (int d = 1; d < 256; d <<= 1) {
        int v = (t >= d) ? tmp[t - d] : 0;
        __syncthreads();
        tmp[t] += v;
        __syncthreads();
    }
    int run = tmp[t] - s4;
    int pre0 = run; run += h0;
    int pre1 = run; run += h1;
    int pre2 = run; run += h2;
    int pre3 = run;
    int pres[4] = {pre0, pre1, pre2, pre3};
#pragma unroll
    for (int j = 0; j < 4; j++) {
        int node = nbase + t * 4 + j;
        if (node < NN) off[node] = c0 + pres[j];
        hist[t * 4 + j] = pres[j];   // reuse as cursor
    }
    if (b == NC - 1 && t == 0) off[NN] = c1;
    __syncthreads();
    for (int e = c0 + t; e < c1; e += 256) {
        int p = epack[e];
        int pos = c0 + atomicAdd(&hist[p >> 17], 1);
        srcs[pos] = p & 0x1FFFF;
    }
}

// graph boundaries from sorted batch
__global__ void bounds_kernel(const int* __restrict__ batch, int* __restrict__ gstart, int n) {
    int i = blockIdx.x * blockDim.x + threadIdx.x;
    if (i >= n) return;
    int b = batch[i];
    int prev = (i == 0) ? -1 : batch[i - 1];
    for (int g = prev + 1; g <= b; g++) gstart[g] = i;
    if (i == n - 1) {
        for (int g = b + 1; g <= GG; g++) gstart[g] = n;
    }
}

// fp32 -> bf16 cast of x (once); block 0 also zeroes ghist (runs BEFORE hist2)
__global__ __launch_bounds__(256) void cast_kernel(const float* __restrict__ x,
                                                   ushort* __restrict__ xb,
                                                   int* __restrict__ ghist) {
    if (blockIdx.x == 0 && threadIdx.x < NC) ghist[threadIdx.x] = 0;
    size_t i = ((size_t)blockIdx.x * blockDim.x + threadIdx.x) * 4;
    if (i >= (size_t)NN * DD) return;
    float4 v = *(const float4*)(x + i);
    ushort4 r;
    r.x = f2b(v.x); r.y = f2b(v.y); r.z = f2b(v.z); r.w = f2b(v.w);
    *(ushort4*)(xb + i) = r;
}

// weights: fp32 [k][n] -> bf16 hi+lo [n][k] (once; one block per matrix)
__global__ __launch_bounds__(256) void prepw_kernel(
    const float* __restrict__ w0a, const float* __restrict__ w0b,
    const float* __restrict__ w1a, const float* __restrict__ w1b,
    const float* __restrict__ w2a, const float* __restrict__ w2b,
    ushort* __restrict__ wt) {
    const float* srcs_[6] = {w0a, w0b, w1a, w1b, w2a, w2b};
    const float* src = srcs_[blockIdx.x];
    ushort* dhi = wt + (size_t)(2 * blockIdx.x) * DD * DD;
    ushort* dlo = wt + (size_t)(2 * blockIdx.x + 1) * DD * DD;
    int t = threadIdx.x;
    int nn = t >> 2, kseg = (t & 3) * 16;
    ushort thi[16], tlo[16];
#pragma unroll
    for (int q = 0; q < 16; q++) {
        float v = src[(size_t)(kseg + q) * DD + nn];
        ushort hh = f2b(v);
        thi[q] = hh;
        tlo[q] = f2b(v - b2f(hh));
    }
    *(uint4*)&dhi[nn * DD + kseg] = *(uint4*)&thi[0];
    *(uint4*)&dhi[nn * DD + kseg + 8] = *(uint4*)&thi[8];
    *(uint4*)&dlo[nn * DD + kseg] = *(uint4*)&tlo[0];
    *(uint4*)&dlo[nn * DD + kseg + 8] = *(uint4*)&tlo[8];
}

// ---------------- aggregation: wave per node, bf16 gather, 8-deep unroll ------
// Round-11 proven local optimum. This round: 32-bit indexing ((s<<6)|lane,
// max 6.4M < 2^31) drops the 64-bit mul+carry per gather.
__global__ __launch_bounds__(256) void agg_kernel(
    const ushort* __restrict__ xb, float* __restrict__ u,
    const int* __restrict__ off, const int* __restrict__ srcs, int n) {
    int node = blockIdx.x * 4 + (threadIdx.x >> 6);
    int lane = threadIdx.x & 63;
    if (node >= n) return;
    int o = off[node];
    int oe = off[node + 1];
    float a0 = b2f(xb[(node << 6) | lane]);   // self
    float a1 = 0.0f, a2 = 0.0f, a3 = 0.0f, a4 = 0.0f, a5 = 0.0f, a6 = 0.0f, a7 = 0.0f;
    int j = o;
    for (; j + 8 <= oe; j += 8) {
        int s0 = srcs[j + 0], s1 = srcs[j + 1], s2 = srcs[j + 2], s3 = srcs[j + 3];
        int s4 = srcs[j + 4], s5 = srcs[j + 5], s6 = srcs[j + 6], s7 = srcs[j + 7];
        ushort v0 = xb[(s0 << 6) | lane];
        ushort v1 = xb[(s1 << 6) | lane];
        ushort v2 = xb[(s2 << 6) | lane];
        ushort v3 = xb[(s3 << 6) | lane];
        ushort v4 = xb[(s4 << 6) | lane];
        ushort v5 = xb[(s5 << 6) | lane];
        ushort v6 = xb[(s6 << 6) | lane];
        ushort v7 = xb[(s7 << 6) | lane];
        a0 += b2f(v0); a1 += b2f(v1); a2 += b2f(v2); a3 += b2f(v3);
        a4 += b2f(v4); a5 += b2f(v5); a6 += b2f(v6); a7 += b2f(v7);
    }
    for (; j + 4 <= oe; j += 4) {
        int s0 = srcs[j + 0], s1 = srcs[j + 1], s2 = srcs[j + 2], s3 = srcs[j + 3];
        ushort v0 = xb[(s0 << 6) | lane];
        ushort v1 = xb[(s1 << 6) | lane];
        ushort v2 = xb[(s2 << 6) | lane];
        ushort v3 = xb[(s3 << 6) | lane];
        a0 += b2f(v0); a1 += b2f(v1); a2 += b2f(v2); a3 += b2f(v3);
    }
    for (; j < oe; j++) a0 += b2f(xb[(srcs[j] << 6) | lane]);
    u[(node << 6) | lane] = ((a0 + a1) + (a2 + a3)) + ((a4 + a5) + (a6 + a7));
}

// ---------------- per-layer MLP via MFMA bf16, split A AND W (r19 proven) -----
// D = Ah@Wh + Al@Wh + Ah@Wl (skip Al@Wl ~ 2^-16 rel) ~= fp32 accuracy.
template <bool HAS_BN, bool OUT_BF16>
__global__ __launch_bounds__(256) void mlpm_kernel(
    const float* __restrict__ u, void* __restrict__ hout,
    const ushort* __restrict__ wah, const ushort* __restrict__ wal,
    const float* __restrict__ ba,
    const ushort* __restrict__ wbh, const ushort* __restrict__ wbl,
    const float* __restrict__ bb,
    const float* __restrict__ bng, const float* __restrict__ bnb,
    const float* __restrict__ bnm, const float* __restrict__ bnv, int n) {
    __shared__ ushort Ahi[DD][PAD];
    __shared__ ushort Alo[DD][PAD];
    __shared__ ushort Wh[DD][PAD];
    __shared__ ushort Wl[DD][PAD];
    int t = threadIdx.x;
    int r0 = blockIdx.x * DD;
    int w = t >> 6, l = t & 63;
    int lr = l & 15, lg = l >> 4;
    int srow = t >> 2, sseg = t & 3;   // staging coords

    // stage A (u -> hi/lo bf16) + W1 hi/lo
    {
        int grow = r0 + srow;
        ushort thi[16], tlo[16];
        if (grow < n) {
            const float4* up = (const float4*)(u + (size_t)grow * DD + sseg * 16);
#pragma unroll
            for (int q = 0; q < 4; q++) {
                float4 v = up[q];
                float vv[4] = {v.x, v.y, v.z, v.w};
#pragma unroll
                for (int c = 0; c < 4; c++) {
                    ushort hh = f2b(vv[c]);
                    thi[q * 4 + c] = hh;
                    tlo[q * 4 + c] = f2b(vv[c] - b2f(hh));
                }
            }
        } else {
#pragma unroll
            for (int q = 0; q < 16; q++) { thi[q] = 0; tlo[q] = 0; }
        }
        *(uint4*)&Ahi[srow][sseg * 16] = *(uint4*)&thi[0];
        *(uint4*)&Ahi[srow][sseg * 16 + 8] = *(uint4*)&thi[8];
        *(uint4*)&Alo[srow][sseg * 16] = *(uint4*)&tlo[0];
        *(uint4*)&Alo[srow][sseg * 16 + 8] = *(uint4*)&tlo[8];
        const uint4* whp = (const uint4*)(wah + srow * DD + sseg * 16);
        *(uint4*)&Wh[srow][sseg * 16] = whp[0];
        *(uint4*)&Wh[srow][sseg * 16 + 8] = whp[1];
        const uint4* wlp = (const uint4*)(wal + srow * DD + sseg * 16);
        *(uint4*)&Wl[srow][sseg * 16] = wlp[0];
        *(uint4*)&Wl[srow][sseg * 16 + 8] = wlp[1];
    }
    __syncthreads();

    // GEMM1: z1 = relu((Ah+Al)@(Wh+Wl) + ba), dropping Al@Wl
    f4_t acc[4];
#pragma unroll
    for (int nt = 0; nt < 4; nt++) acc[nt] = (f4_t){0.0f, 0.0f, 0.0f, 0.0f};
#pragma unroll
    for (int ks = 0; ks < 2; ks++) {
        bf8_t ah = *(const bf8_t*)&Ahi[w * 16 + lr][ks * 32 + lg * 8];
        bf8_t al = *(const bf8_t*)&Alo[w * 16 + lr][ks * 32 + lg * 8];
#pragma unroll
        for (int nt = 0; nt < 4; nt++) {
            bf8_t bh = *(const bf8_t*)&Wh[nt * 16 + lr][ks * 32 + lg * 8];
            bf8_t bl = *(const bf8_t*)&Wl[nt * 16 + lr][ks * 32 + lg * 8];
            acc[nt] = __builtin_amdgcn_mfma_f32_16x16x32_bf16(ah, bh, acc[nt], 0, 0, 0);
            acc[nt] = __builtin_amdgcn_mfma_f32_16x16x32_bf16(al, bh, acc[nt], 0, 0, 0);
            acc[nt] = __builtin_amdgcn_mfma_f32_16x16x32_bf16(ah, bl, acc[nt], 0, 0, 0);
        }
    }
    // z1 hi/lo -> alias into Ahi/Alo (wave-own rows only)
#pragma unroll
    for (int nt = 0; nt < 4; nt++) {
        float bav = ba[nt * 16 + lr];
#pragma unroll
        for (int r = 0; r < 4; r++) {
            float z = relu_f(acc[nt][r] + bav);
            ushort zh = f2b(z);
            Ahi[w * 16 + lg * 4 + r][nt * 16 + lr] = zh;
            Alo[w * 16 + lg * 4 + r][nt * 16 + lr] = f2b(z - b2f(zh));
        }
    }
    __syncthreads();   // GEMM1 W-reads + Z-writes complete

    // re-stage Wh/Wl with W2
    {
        const uint4* whp = (const uint4*)(wbh + srow * DD + sseg * 16);
        *(uint4*)&Wh[srow][sseg * 16] = whp[0];
        *(uint4*)&Wh[srow][sseg * 16 + 8] = whp[1];
        const uint4* wlp = (const uint4*)(wbl + srow * DD + sseg * 16);
        *(uint4*)&Wl[srow][sseg * 16] = wlp[0];
        *(uint4*)&Wl[srow][sseg * 16 + 8] = wlp[1];
    }
    __syncthreads();

    // GEMM2: z2 = (Zh+Zl)@(Wh+Wl), dropping Zl@Wl
    f4_t acc2[4];
#pragma unroll
    for (int nt = 0; nt < 4; nt++) acc2[nt] = (f4_t){0.0f, 0.0f, 0.0f, 0.0f};
#pragma unroll
    for (int ks = 0; ks < 2; ks++) {
        bf8_t ah = *(const bf8_t*)&Ahi[w * 16 + lr][ks * 32 + lg * 8];
        bf8_t al = *(const bf8_t*)&Alo[w * 16 + lr][ks * 32 + lg * 8];
#pragma unroll
        for (int nt = 0; nt < 4; nt++) {
            bf8_t bh = *(const bf8_t*)&Wh[nt * 16 + lr][ks * 32 + lg * 8];
            bf8_t bl = *(const bf8_t*)&Wl[nt * 16 + lr][ks * 32 + lg * 8];
            acc2[nt] = __builtin_amdgcn_mfma_f32_16x16x32_bf16(ah, bh, acc2[nt], 0, 0, 0);
            acc2[nt] = __builtin_amdgcn_mfma_f32_16x16x32_bf16(al, bh, acc2[nt], 0, 0, 0);
            acc2[nt] = __builtin_amdgcn_mfma_f32_16x16x32_bf16(ah, bl, acc2[nt], 0, 0, 0);
        }
    }

    // epilogue: +bb, relu, [BN], store
#pragma unroll
    for (int nt = 0; nt < 4; nt++) {
        int col = nt * 16 + lr;
        float bbv = bb[col];
        float sc = 1.0f, sh = 0.0f;
        if (HAS_BN) {
            sc = bng[col] * rsqrtf(bnv[col] + 1e-5f);
            sh = bnb[col] - bnm[col] * sc;
        }
#pragma unroll
        for (int r = 0; r < 4; r++) {
            int row = r0 + w * 16 + lg * 4 + r;
            if (row < n) {
                float v = relu_f(acc2[nt][r] + bbv);
                if (HAS_BN) v = fmaf(v, sc, sh);
                if (OUT_BF16) ((ushort*)hout)[(size_t)row * DD + col] = f2b(v);
                else ((float*)hout)[(size_t)row * DD + col] = v;
            }
        }
    }
}

// ---------------- fused pooling + head: one block per graph (r15 validated) --
__global__ __launch_bounds__(256) void poolhead_kernel(
    const float* __restrict__ h, const int* __restrict__ gstart,
    const float* __restrict__ wp1, const float* __restrict__ bp1,
    const float* __restrict__ wp2, const float* __restrict__ bp2,
    float* __restrict__ out) {
    __shared__ float ssum[4][DD];
    __shared__ float smax[4][DD];
    __shared__ float gx[2 * DD];
    int g = blockIdx.x;
    int lane = threadIdx.x & 63;
    int wave = threadIdx.x >> 6;
    int s = gstart[g], e = gstart[g + 1];
    float sum = 0.0f, mx = 0.0f;  // layer-2 out is post-ReLU >= 0; 0 == empty-graph guard
    for (int i = s + wave; i < e; i += 4) {
        float v = h[(size_t)i * DD + lane];
        sum += v;
        mx = fmaxf(mx, v);
    }
    ssum[wave][lane] = sum;
    smax[wave][lane] = mx;
    __syncthreads();
    if (wave == 0) {
        sum = ssum[0][lane] + ssum[1][lane] + ssum[2][lane] + ssum[3][lane];
        mx = fmaxf(fmaxf(smax[0][lane], smax[1][lane]),
                   fmaxf(smax[2][lane], smax[3][lane]));
        float cnt = fmaxf((float)(e - s), 1.0f);
        gx[lane] = sum / cnt;
        gx[DD + lane] = mx;
    }
    __syncthreads();
    if (wave == 0) {
        float tt = bp1[lane];
        for (int k = 0; k < 2 * DD; k++) tt = fmaf(gx[k], wp1[k * DD + lane], tt);
        float p0 = tt * wp2[lane * 2 + 0];
        float p1 = tt * wp2[lane * 2 + 1];
        for (int o = 32; o > 0; o >>= 1) {
            p0 += __shfl_down(p0, o);
            p1 += __shfl_down(p1, o);
        }
        if (lane == 0) {
            p0 += bp2[0];
            p1 += bp2[1];
            float m = fmaxf(p0, p1);
            float lse = m + logf(expf(p0 - m) + expf(p1 - m));
            out[g * 2 + 0] = p0 - lse;
            out[g * 2 + 1] = p1 - lse;
        }
    }
}

// ---------------- launch ----------------
extern "C" void kernel_launch(void* const* d_in, const int* in_sizes, int n_in,
                              void* d_out, int out_size, void* d_ws, size_t ws_size,
                              hipStream_t stream) {
    const float* x     = (const float*)d_in[0];
    const int*   ei    = (const int*)d_in[1];
    const int*   batch = (const int*)d_in[2];
    const float* w0a = (const float*)d_in[3];  const float* b0a = (const float*)d_in[4];
    const float* w0b = (const float*)d_in[5];  const float* b0b = (const float*)d_in[6];
    const float* w1a = (const float*)d_in[7];  const float* b1a = (const float*)d_in[8];
    const float* w1b = (const float*)d_in[9];  const float* b1b = (const float*)d_in[10];
    const float* w2a = (const float*)d_in[11]; const float* b2a = (const float*)d_in[12];
    const float* w2b = (const float*)d_in[13]; const float* b2b = (const float*)d_in[14];
    const float* bn0g = (const float*)d_in[15]; const float* bn0b = (const float*)d_in[16];
    const float* bn0m = (const float*)d_in[17]; const float* bn0v = (const float*)d_in[18];
    const float* bn1g = (const float*)d_in[19]; const float* bn1b = (const float*)d_in[20];
    const float* bn1m = (const float*)d_in[21]; const float* bn1v = (const float*)d_in[22];
    const float* wp1 = (const float*)d_in[23]; const float* bp1 = (const float*)d_in[24];
    const float* wp2 = (const float*)d_in[25]; const float* bp2 = (const float*)d_in[26];
    float* out = (float*)d_out;

    char* p = (char*)d_ws;
    auto take = [&](size_t bytes) {
        char* r = p;
        p += (bytes + 255) & ~(size_t)255;
        return r;
    };
    int* ghist   = (int*)take(NC * sizeof(int));
    int* coffs   = (int*)take((NC + 1) * sizeof(int));
    int* gcursor = (int*)take(NC * sizeof(int));
    int* epack   = (int*)take(EE * sizeof(int));
    int* srcs    = (int*)take(EE * sizeof(int));
    int* off     = (int*)take((NN + 1) * sizeof(int));
    int* gstart  = (int*)take((GG + 1) * sizeof(int));
    ushort* xb   = (ushort*)take((size_t)NN * DD * sizeof(ushort));
    float* bufU  = (float*)take((size_t)NN * DD * sizeof(float));
    ushort* hA   = (ushort*)take((size_t)NN * DD * sizeof(ushort));
    ushort* hB   = (ushort*)take((size_t)NN * DD * sizeof(ushort));
    float* hC    = (float*)take((size_t)NN * DD * sizeof(float));
    ushort* wt   = (ushort*)take(12 * DD * DD * sizeof(ushort));   // bf16 hi/lo [n][k] x6

    // cast first (also zeroes ghist) -> CSR build -> bounds -> weight prep
    cast_kernel<<<(NN * DD / 4 + 255) / 256, 256, 0, stream>>>(x, xb, ghist);
    hist2_kernel<<<512, 256, 0, stream>>>(ei + EE, ghist, EE);
    scan2_kernel<<<1, 128, 0, stream>>>(ghist, coffs, gcursor);
    bin_kernel<<<512, 256, 0, stream>>>(ei, gcursor, epack, EE);
    csr2_kernel<<<NC, 256, 0, stream>>>(epack, coffs, srcs, off);
    bounds_kernel<<<(NN + 255) / 256, 256, 0, stream>>>(batch, gstart, NN);
    prepw_kernel<<<6, 256, 0, stream>>>(w0a, w0b, w1a, w1b, w2a, w2b, wt);

    int agg_grid = (NN + 3) / 4;
    int mlp_grid = (NN + DD - 1) / DD;   // 1563 blocks of 64 nodes
    const size_t M = (size_t)DD * DD;
    ushort* w0ah = wt + 0 * M;  ushort* w0al = wt + 1 * M;
    ushort* w0bh = wt + 2 * M;  ushort* w0bl = wt + 3 * M;
    ushort* w1ah = wt + 4 * M;  ushort* w1al = wt + 5 * M;
    ushort* w1bh = wt + 6 * M;  ushort* w1bl = wt + 7 * M;
    ushort* w2ah = wt + 8 * M;  ushort* w2al = wt + 9 * M;
    ushort* w2bh = wt + 10 * M; ushort* w2bl = wt + 11 * M;

    // layer 0
    agg_kernel<<<agg_grid, 256, 0, stream>>>(xb, bufU, off, srcs, NN);
    mlpm_kernel<true, true><<<mlp_grid, 256, 0, stream>>>(
        bufU, hA, w0ah, w0al, b0a, w0bh, w0bl, b0b, bn0g, bn0b, bn0m, bn0v, NN);
    // layer 1
    agg_kernel<<<agg_grid, 256, 0, stream>>>(hA, bufU, off, srcs, NN);
    mlpm_kernel<true, true><<<mlp_grid, 256, 0, stream>>>(
        bufU, hB, w1ah, w1al, b1a, w1bh, w1bl, b1b, bn1g, bn1b, bn1m, bn1v, NN);
    // layer 2 (fp32 out)
    agg_kernel<<<agg_grid, 256, 0, stream>>>(hB, bufU, off, srcs, NN);
    mlpm_kernel<false, false><<<mlp_grid, 256, 0, stream>>>(
        bufU, hC, w2ah, w2al, b2a, w2bh, w2bl, b2b, nullptr, nullptr, nullptr, nullptr, NN);

    // fused pooling + head
    poolhead_kernel<<<GG, 256, 0, stream>>>(hC, gstart, wp1, bp1, wp2, bp2, out);
}